// Round 3
// baseline (1268.523 us; speedup 1.0000x reference)
//
#include <hip/hip_runtime.h>

// ---------------------------------------------------------------------------
// GINE edge model: conv1(387->128 via linearity trick) -> conv2(128) -> edge head
// f32 in/out; bf16 MFMA (16x16x32) with f32 accumulation for the big GEMMs.
// ---------------------------------------------------------------------------

using f32x4 = __attribute__((ext_vector_type(4))) float;
using s16x8 = __attribute__((ext_vector_type(8))) short;

#define N_NODES 100000
#define N_EDGES 600000
#define NODE_IN 387
#define KPAD    416   // 13 * 32
#define HID     128

__device__ __forceinline__ unsigned short f2bf(float f) {
    unsigned u = __float_as_uint(f);
    u += 0x7FFFu + ((u >> 16) & 1u);   // RNE
    return (unsigned short)(u >> 16);
}

// --------------------------- edge_index decode -----------------------------
__global__ __launch_bounds__(256) void k_decode(const unsigned* __restrict__ w,
                                                int* __restrict__ s32,
                                                int* __restrict__ d32) {
    __shared__ unsigned long long bs[4];
    __shared__ int is64_s;
    const int t = threadIdx.x;
    unsigned any = 0;
    for (int i = 1 + 2 * t; i < 2048; i += 512) any |= w[i];
    unsigned long long b = __ballot(any != 0);
    if ((t & 63) == 0) bs[t >> 6] = b;
    __syncthreads();
    if (t == 0) is64_s = ((bs[0] | bs[1] | bs[2] | bs[3]) == 0ULL) ? 1 : 0;
    __syncthreads();
    const int is64 = is64_s;
    const int e = blockIdx.x * 256 + t;
    if (e < N_EDGES) {
        if (is64) {
            s32[e] = (int)w[2 * e];
            d32[e] = (int)w[2 * N_EDGES + 2 * e];
        } else {
            s32[e] = (int)w[e];
            d32[e] = (int)w[N_EDGES + e];
        }
    }
}

// ------------------------ weight transpose + bf16 --------------------------
__global__ __launch_bounds__(256) void k_prep(const float* __restrict__ w1,
                                              const float* __restrict__ w2,
                                              const float* __restrict__ v1,
                                              const float* __restrict__ v2,
                                              const float* __restrict__ ew1,
                                              unsigned short* __restrict__ W1t,
                                              unsigned short* __restrict__ W2t,
                                              unsigned short* __restrict__ V1t,
                                              unsigned short* __restrict__ V2t,
                                              unsigned short* __restrict__ EW1t) {
    int i = blockIdx.x * 256 + threadIdx.x;
    if (i < 128 * KPAD) {
        int c = i / KPAD, k = i - c * KPAD;
        W1t[i] = (k < NODE_IN) ? f2bf(w1[k * HID + c]) : (unsigned short)0;
        return;
    }
    i -= 128 * KPAD;
    if (i < 16384) { int c = i >> 7, k = i & 127; W2t[i] = f2bf(w2[k * HID + c]); return; }
    i -= 16384;
    if (i < 16384) { int c = i >> 7, k = i & 127; V1t[i] = f2bf(v1[k * HID + c]); return; }
    i -= 16384;
    if (i < 16384) { int c = i >> 7, k = i & 127; V2t[i] = f2bf(v2[k * HID + c]); return; }
    i -= 16384;
    if (i < 32768) { int c = i >> 8, k = i & 255; EW1t[i] = f2bf(ew1[k * HID + c]); return; }
}

// Full B-tile staging: 128 cols x 32 k bf16 -> 256 threads x 16 shorts.
#define STAGE_B(dst, srcbase, stride_) do {                                   \
    const int col_ = t >> 1, h_ = t & 1;                                      \
    *(s16x8*)&(dst)[col_ * 40 + h_ * 16] =                                    \
        *(const s16x8*)&(srcbase)[col_ * (stride_) + h_ * 16];                \
    *(s16x8*)&(dst)[col_ * 40 + h_ * 16 + 8] =                                \
        *(const s16x8*)&(srcbase)[col_ * (stride_) + h_ * 16 + 8];            \
} while (0)

// ----------------- conv1: per-edge msg GEMM + scatter-add ------------------
// yagg[dst] += relu(x[src] + ea@e1_w + e1_b) @ m1_w1     (A computed on the fly)
__global__ __launch_bounds__(256) void k_edge1(const float* __restrict__ x,
                                               const int* __restrict__ srcp,
                                               const int* __restrict__ dstp,
                                               const float* __restrict__ ea,
                                               const float* __restrict__ e1w,
                                               const float* __restrict__ e1b,
                                               const unsigned short* __restrict__ W1t,
                                               float* __restrict__ yagg) {
    __shared__ __align__(16) unsigned short Asm[64 * 40];
    __shared__ __align__(16) unsigned short Bsm[128 * 40];
    __shared__ float e1w_s[7 * KPAD];
    __shared__ float e1b_s[KPAD];
    __shared__ float ea_s[64 * 8];
    __shared__ int src_s[64];
    __shared__ int dst_s[64];
    const int t = threadIdx.x;
    const int e0 = blockIdx.x * 64;

    for (int i = t; i < 7 * KPAD; i += 256) {
        int q = i / KPAD, k = i - q * KPAD;
        e1w_s[i] = (k < NODE_IN) ? e1w[q * NODE_IN + k] : 0.f;
    }
    for (int i = t; i < KPAD; i += 256) e1b_s[i] = (i < NODE_IN) ? e1b[i] : 0.f;
    for (int i = t; i < 64 * 7; i += 256) {
        int r = i / 7, q = i - r * 7;
        ea_s[r * 8 + q] = ea[(e0 + r) * 7 + q];
    }
    if (t < 64) src_s[t] = srcp[e0 + t];
    else if (t < 128) dst_s[t - 64] = dstp[e0 + (t - 64)];
    __syncthreads();

    const int lane = t & 63, wid = t >> 6;
    const int wr = wid >> 1, wc = wid & 1;
    const int r = t >> 2, kc = (t & 3) * 8;
    const int srow = src_s[r];
    float eav[7];
#pragma unroll
    for (int q = 0; q < 7; ++q) eav[q] = ea_s[r * 8 + q];

    f32x4 acc[2][4];
    const f32x4 zero = {0.f, 0.f, 0.f, 0.f};
#pragma unroll
    for (int mi = 0; mi < 2; ++mi)
#pragma unroll
        for (int ni = 0; ni < 4; ++ni) acc[mi][ni] = zero;

    for (int ks = 0; ks < 13; ++ks) {
        {   // A stage: msg tile 64x32 bf16
            const int kb = ks * 32 + kc;
            s16x8 v;
#pragma unroll
            for (int j = 0; j < 8; ++j) {
                const int k = kb + j;
                float val = 0.f;
                if (k < NODE_IN) {
                    float le = e1b_s[k];
#pragma unroll
                    for (int q = 0; q < 7; ++q) le = fmaf(eav[q], e1w_s[q * KPAD + k], le);
                    val = x[srow * NODE_IN + k] + le;
                    val = fmaxf(val, 0.f);
                }
                v[j] = (short)f2bf(val);
            }
            *(s16x8*)&Asm[r * 40 + kc] = v;
        }
        STAGE_B(Bsm, &W1t[ks * 32], KPAD);
        __syncthreads();
        const int koff = (lane >> 4) * 8;
        const int rA = lane & 15;
        s16x8 a0 = *(const s16x8*)&Asm[(wr * 32 + rA) * 40 + koff];
        s16x8 a1 = *(const s16x8*)&Asm[(wr * 32 + 16 + rA) * 40 + koff];
#pragma unroll
        for (int ni = 0; ni < 4; ++ni) {
            s16x8 b = *(const s16x8*)&Bsm[(wc * 64 + ni * 16 + rA) * 40 + koff];
            acc[0][ni] = __builtin_amdgcn_mfma_f32_16x16x32_bf16(a0, b, acc[0][ni], 0, 0, 0);
            acc[1][ni] = __builtin_amdgcn_mfma_f32_16x16x32_bf16(a1, b, acc[1][ni], 0, 0, 0);
        }
        __syncthreads();
    }
    // scatter-add epilogue
    const int cbase = wc * 64 + (lane & 15);
#pragma unroll
    for (int mi = 0; mi < 2; ++mi) {
#pragma unroll
        for (int reg = 0; reg < 4; ++reg) {
            const int rr = wr * 32 + mi * 16 + (lane >> 4) * 4 + reg;
            const int d = dst_s[rr];
#pragma unroll
            for (int ni = 0; ni < 4; ++ni)
                atomicAdd(&yagg[d * HID + cbase + ni * 16], acc[mi][ni][reg]);
        }
    }
}

// -------------- node MLP1: r1 = relu(relu(x@W1 + yagg + b1)@W2 + b2) -------
__global__ __launch_bounds__(256) void k_node1(const float* __restrict__ x,
                                               const float* __restrict__ yagg,
                                               const unsigned short* __restrict__ W1t,
                                               const unsigned short* __restrict__ W2t,
                                               const float* __restrict__ b1,
                                               const float* __restrict__ b2,
                                               float* __restrict__ r1) {
    __shared__ __align__(16) unsigned short Asm[64 * 40];
    __shared__ __align__(16) unsigned short Bsm[128 * 40];
    __shared__ __align__(16) unsigned short Hsm[64 * 136];
    const int t = threadIdx.x;
    const int i0 = blockIdx.x * 64;
    const int lane = t & 63, wid = t >> 6, wr = wid >> 1, wc = wid & 1;
    const int r = t >> 2, kc = (t & 3) * 8;
    const int rg = i0 + r;
    const bool rvalid = rg < N_NODES;

    f32x4 acc[2][4];
    const f32x4 zero = {0.f, 0.f, 0.f, 0.f};
#pragma unroll
    for (int mi = 0; mi < 2; ++mi)
#pragma unroll
        for (int ni = 0; ni < 4; ++ni) acc[mi][ni] = zero;

    for (int ks = 0; ks < 13; ++ks) {
        {
            const int kb = ks * 32 + kc;
            s16x8 v;
#pragma unroll
            for (int j = 0; j < 8; ++j) {
                const int k = kb + j;
                float val = (rvalid && k < NODE_IN) ? x[rg * NODE_IN + k] : 0.f;
                v[j] = (short)f2bf(val);
            }
            *(s16x8*)&Asm[r * 40 + kc] = v;
        }
        STAGE_B(Bsm, &W1t[ks * 32], KPAD);
        __syncthreads();
        const int koff = (lane >> 4) * 8;
        const int rA = lane & 15;
        s16x8 a0 = *(const s16x8*)&Asm[(wr * 32 + rA) * 40 + koff];
        s16x8 a1 = *(const s16x8*)&Asm[(wr * 32 + 16 + rA) * 40 + koff];
#pragma unroll
        for (int ni = 0; ni < 4; ++ni) {
            s16x8 b = *(const s16x8*)&Bsm[(wc * 64 + ni * 16 + rA) * 40 + koff];
            acc[0][ni] = __builtin_amdgcn_mfma_f32_16x16x32_bf16(a0, b, acc[0][ni], 0, 0, 0);
            acc[1][ni] = __builtin_amdgcn_mfma_f32_16x16x32_bf16(a1, b, acc[1][ni], 0, 0, 0);
        }
        __syncthreads();
    }
    // layer1 epilogue -> hidden (bf16 in LDS, A-layout, padded stride 136)
    const int jb = wc * 64 + (lane & 15);
#pragma unroll
    for (int mi = 0; mi < 2; ++mi) {
#pragma unroll
        for (int reg = 0; reg < 4; ++reg) {
            const int rloc = wr * 32 + mi * 16 + (lane >> 4) * 4 + reg;
            const int rowg = i0 + rloc;
#pragma unroll
            for (int ni = 0; ni < 4; ++ni) {
                const int j = jb + ni * 16;
                float v = acc[mi][ni][reg];
                if (rowg < N_NODES) {
                    v += yagg[rowg * HID + j] + b1[j];
                    v = fmaxf(v, 0.f);
                } else v = 0.f;
                Hsm[rloc * 136 + j] = f2bf(v);
            }
        }
    }
    __syncthreads();
    // layer 2
    f32x4 acc2[2][4];
#pragma unroll
    for (int mi = 0; mi < 2; ++mi)
#pragma unroll
        for (int ni = 0; ni < 4; ++ni) acc2[mi][ni] = zero;

    for (int ks = 0; ks < 4; ++ks) {
        STAGE_B(Bsm, &W2t[ks * 32], HID);
        __syncthreads();
        const int koff = (lane >> 4) * 8;
        const int rA = lane & 15;
        s16x8 a0 = *(const s16x8*)&Hsm[(wr * 32 + rA) * 136 + ks * 32 + koff];
        s16x8 a1 = *(const s16x8*)&Hsm[(wr * 32 + 16 + rA) * 136 + ks * 32 + koff];
#pragma unroll
        for (int ni = 0; ni < 4; ++ni) {
            s16x8 b = *(const s16x8*)&Bsm[(wc * 64 + ni * 16 + rA) * 40 + koff];
            acc2[0][ni] = __builtin_amdgcn_mfma_f32_16x16x32_bf16(a0, b, acc2[0][ni], 0, 0, 0);
            acc2[1][ni] = __builtin_amdgcn_mfma_f32_16x16x32_bf16(a1, b, acc2[1][ni], 0, 0, 0);
        }
        __syncthreads();
    }
#pragma unroll
    for (int mi = 0; mi < 2; ++mi) {
#pragma unroll
        for (int reg = 0; reg < 4; ++reg) {
            const int rloc = wr * 32 + mi * 16 + (lane >> 4) * 4 + reg;
            const int rowg = i0 + rloc;
            if (rowg < N_NODES) {
#pragma unroll
                for (int ni = 0; ni < 4; ++ni) {
                    const int j = jb + ni * 16;
                    float v = acc2[mi][ni][reg] + b2[j];
                    r1[rowg * HID + j] = fmaxf(v, 0.f);
                }
            }
        }
    }
}

// -------------- conv2 message pass: agg2[dst] += relu(r1[src]+ea@e2w+b) ----
__global__ __launch_bounds__(256) void k_edge2(const float* __restrict__ r1,
                                               const int* __restrict__ srcp,
                                               const int* __restrict__ dstp,
                                               const float* __restrict__ ea,
                                               const float* __restrict__ e2w,
                                               const float* __restrict__ e2b,
                                               float* __restrict__ agg2) {
    __shared__ float w_s[7 * HID];
    __shared__ float b_s[HID];
    const int t = threadIdx.x;
    for (int i = t; i < 7 * HID; i += 256) w_s[i] = e2w[i];
    if (t < HID) b_s[t] = e2b[t];
    __syncthreads();
    const int wid = t >> 6, lane = t & 63;
    const int e = blockIdx.x * 4 + wid;
    const int s = srcp[e], d = dstp[e];
    float eav[7];
#pragma unroll
    for (int q = 0; q < 7; ++q) eav[q] = ea[e * 7 + q];
#pragma unroll
    for (int h = 0; h < 2; ++h) {
        const int dd = lane + h * 64;
        float v = r1[s * HID + dd] + b_s[dd];
#pragma unroll
        for (int q = 0; q < 7; ++q) v = fmaf(eav[q], w_s[q * HID + dd], v);
        v = fmaxf(v, 0.f);
        atomicAdd(&agg2[d * HID + dd], v);
    }
}

// -------- node MLP2: r2 = bf16(relu(relu((r1+agg2)@V1 + b1)@V2 + b2)) ------
__global__ __launch_bounds__(256) void k_node2(const float* __restrict__ r1,
                                               const float* __restrict__ agg2,
                                               const unsigned short* __restrict__ V1t,
                                               const unsigned short* __restrict__ V2t,
                                               const float* __restrict__ b1,
                                               const float* __restrict__ b2,
                                               unsigned short* __restrict__ r2) {
    __shared__ __align__(16) unsigned short Asm[64 * 40];
    __shared__ __align__(16) unsigned short Bsm[128 * 40];
    __shared__ __align__(16) unsigned short Hsm[64 * 136];
    const int t = threadIdx.x;
    const int i0 = blockIdx.x * 64;
    const int lane = t & 63, wid = t >> 6, wr = wid >> 1, wc = wid & 1;
    const int r = t >> 2, kc = (t & 3) * 8;
    const int rg = i0 + r;
    const bool rvalid = rg < N_NODES;

    f32x4 acc[2][4];
    const f32x4 zero = {0.f, 0.f, 0.f, 0.f};
#pragma unroll
    for (int mi = 0; mi < 2; ++mi)
#pragma unroll
        for (int ni = 0; ni < 4; ++ni) acc[mi][ni] = zero;

    for (int ks = 0; ks < 4; ++ks) {
        {
            const int kb = ks * 32 + kc;
            s16x8 v;
            if (rvalid) {
                const f32x4* pa = (const f32x4*)&r1[rg * HID + kb];
                const f32x4* pb = (const f32x4*)&agg2[rg * HID + kb];
                f32x4 u0 = pa[0], u1 = pa[1], w0 = pb[0], w1 = pb[1];
#pragma unroll
                for (int j = 0; j < 4; ++j) v[j] = (short)f2bf(u0[j] + w0[j]);
#pragma unroll
                for (int j = 0; j < 4; ++j) v[4 + j] = (short)f2bf(u1[j] + w1[j]);
            } else {
#pragma unroll
                for (int j = 0; j < 8; ++j) v[j] = 0;
            }
            *(s16x8*)&Asm[r * 40 + kc] = v;
        }
        STAGE_B(Bsm, &V1t[ks * 32], HID);
        __syncthreads();
        const int koff = (lane >> 4) * 8;
        const int rA = lane & 15;
        s16x8 a0 = *(const s16x8*)&Asm[(wr * 32 + rA) * 40 + koff];
        s16x8 a1 = *(const s16x8*)&Asm[(wr * 32 + 16 + rA) * 40 + koff];
#pragma unroll
        for (int ni = 0; ni < 4; ++ni) {
            s16x8 b = *(const s16x8*)&Bsm[(wc * 64 + ni * 16 + rA) * 40 + koff];
            acc[0][ni] = __builtin_amdgcn_mfma_f32_16x16x32_bf16(a0, b, acc[0][ni], 0, 0, 0);
            acc[1][ni] = __builtin_amdgcn_mfma_f32_16x16x32_bf16(a1, b, acc[1][ni], 0, 0, 0);
        }
        __syncthreads();
    }
    const int jb = wc * 64 + (lane & 15);
#pragma unroll
    for (int mi = 0; mi < 2; ++mi) {
#pragma unroll
        for (int reg = 0; reg < 4; ++reg) {
            const int rloc = wr * 32 + mi * 16 + (lane >> 4) * 4 + reg;
            const int rowg = i0 + rloc;
#pragma unroll
            for (int ni = 0; ni < 4; ++ni) {
                const int j = jb + ni * 16;
                float v = acc[mi][ni][reg];
                if (rowg < N_NODES) {
                    v += b1[j];
                    v = fmaxf(v, 0.f);
                } else v = 0.f;
                Hsm[rloc * 136 + j] = f2bf(v);
            }
        }
    }
    __syncthreads();
    f32x4 acc2[2][4];
#pragma unroll
    for (int mi = 0; mi < 2; ++mi)
#pragma unroll
        for (int ni = 0; ni < 4; ++ni) acc2[mi][ni] = zero;

    for (int ks = 0; ks < 4; ++ks) {
        STAGE_B(Bsm, &V2t[ks * 32], HID);
        __syncthreads();
        const int koff = (lane >> 4) * 8;
        const int rA = lane & 15;
        s16x8 a0 = *(const s16x8*)&Hsm[(wr * 32 + rA) * 136 + ks * 32 + koff];
        s16x8 a1 = *(const s16x8*)&Hsm[(wr * 32 + 16 + rA) * 136 + ks * 32 + koff];
#pragma unroll
        for (int ni = 0; ni < 4; ++ni) {
            s16x8 b = *(const s16x8*)&Bsm[(wc * 64 + ni * 16 + rA) * 40 + koff];
            acc2[0][ni] = __builtin_amdgcn_mfma_f32_16x16x32_bf16(a0, b, acc2[0][ni], 0, 0, 0);
            acc2[1][ni] = __builtin_amdgcn_mfma_f32_16x16x32_bf16(a1, b, acc2[1][ni], 0, 0, 0);
        }
        __syncthreads();
    }
#pragma unroll
    for (int mi = 0; mi < 2; ++mi) {
#pragma unroll
        for (int reg = 0; reg < 4; ++reg) {
            const int rloc = wr * 32 + mi * 16 + (lane >> 4) * 4 + reg;
            const int rowg = i0 + rloc;
            if (rowg < N_NODES) {
#pragma unroll
                for (int ni = 0; ni < 4; ++ni) {
                    const int j = jb + ni * 16;
                    float v = acc2[mi][ni][reg] + b2[j];
                    r2[rowg * HID + j] = f2bf(fmaxf(v, 0.f));
                }
            }
        }
    }
}

// ------- edge head: out = relu([r2_s|r2_d|ea] @ em_w1 + b1) @ em_w2 + b2 ---
__global__ __launch_bounds__(256) void k_head(const unsigned short* __restrict__ r2,
                                              const int* __restrict__ srcp,
                                              const int* __restrict__ dstp,
                                              const float* __restrict__ ea,
                                              const unsigned short* __restrict__ EW1t,
                                              const float* __restrict__ emw1,
                                              const float* __restrict__ emb1,
                                              const float* __restrict__ emw2,
                                              const float* __restrict__ emb2,
                                              float* __restrict__ out) {
    __shared__ __align__(16) unsigned short Asm[64 * 40];
    __shared__ __align__(16) unsigned short Bsm[128 * 40];
    __shared__ float Hsm[64 * 129];
    __shared__ float ew_ea[7 * HID];
    __shared__ float eb1_s[HID];
    __shared__ float w2_s[256];
    __shared__ float b2_s[2];
    __shared__ float ea_s[64 * 8];
    __shared__ int src_s[64];
    __shared__ int dst_s[64];
    __shared__ float red[512];
    const int t = threadIdx.x;
    const int e0 = blockIdx.x * 64;

    for (int i = t; i < 7 * HID; i += 256) ew_ea[i] = emw1[256 * HID + i];
    if (t < HID) eb1_s[t] = emb1[t];
    for (int i = t; i < 256; i += 256) w2_s[i] = emw2[i];
    if (t < 2) b2_s[t] = emb2[t];
    for (int i = t; i < 64 * 7; i += 256) {
        int r = i / 7, q = i - r * 7;
        ea_s[r * 8 + q] = ea[(e0 + r) * 7 + q];
    }
    if (t < 64) src_s[t] = srcp[e0 + t];
    else if (t < 128) dst_s[t - 64] = dstp[e0 + (t - 64)];
    __syncthreads();

    const int lane = t & 63, wid = t >> 6, wr = wid >> 1, wc = wid & 1;
    const int r = t >> 2, kc = (t & 3) * 8;

    f32x4 acc[2][4];
    const f32x4 zero = {0.f, 0.f, 0.f, 0.f};
#pragma unroll
    for (int mi = 0; mi < 2; ++mi)
#pragma unroll
        for (int ni = 0; ni < 4; ++ni) acc[mi][ni] = zero;

    for (int ks = 0; ks < 8; ++ks) {
        {   // A stage: gathered r2 rows (bf16, direct copy)
            const int k = ks * 32 + kc;
            const unsigned short* p = (k < HID) ? &r2[src_s[r] * HID + k]
                                                : &r2[dst_s[r] * HID + (k - HID)];
            *(s16x8*)&Asm[r * 40 + kc] = *(const s16x8*)p;
        }
        STAGE_B(Bsm, &EW1t[ks * 32], 256);
        __syncthreads();
        const int koff = (lane >> 4) * 8;
        const int rA = lane & 15;
        s16x8 a0 = *(const s16x8*)&Asm[(wr * 32 + rA) * 40 + koff];
        s16x8 a1 = *(const s16x8*)&Asm[(wr * 32 + 16 + rA) * 40 + koff];
#pragma unroll
        for (int ni = 0; ni < 4; ++ni) {
            s16x8 b = *(const s16x8*)&Bsm[(wc * 64 + ni * 16 + rA) * 40 + koff];
            acc[0][ni] = __builtin_amdgcn_mfma_f32_16x16x32_bf16(a0, b, acc[0][ni], 0, 0, 0);
            acc[1][ni] = __builtin_amdgcn_mfma_f32_16x16x32_bf16(a1, b, acc[1][ni], 0, 0, 0);
        }
        __syncthreads();
    }
    // layer1 epilogue: + ea part (f32 exact) + bias, relu -> Hsm (stride 129)
    const int jb = wc * 64 + (lane & 15);
#pragma unroll
    for (int mi = 0; mi < 2; ++mi) {
#pragma unroll
        for (int reg = 0; reg < 4; ++reg) {
            const int rloc = wr * 32 + mi * 16 + (lane >> 4) * 4 + reg;
#pragma unroll
            for (int ni = 0; ni < 4; ++ni) {
                const int j = jb + ni * 16;
                float v = acc[mi][ni][reg] + eb1_s[j];
#pragma unroll
                for (int q = 0; q < 7; ++q)
                    v = fmaf(ea_s[rloc * 8 + q], ew_ea[q * HID + j], v);
                Hsm[rloc * 129 + j] = fmaxf(v, 0.f);
            }
        }
    }
    __syncthreads();
    // layer2: hid[128] @ em_w2[128][2]
    {
        const int e = t & 63, p = t >> 6;
        const float* hb = &Hsm[e * 129 + p * 32];
        float s0 = 0.f, s1 = 0.f;
#pragma unroll
        for (int j = 0; j < 32; ++j) {
            const float h = hb[j];
            s0 = fmaf(h, w2_s[(p * 32 + j) * 2], s0);
            s1 = fmaf(h, w2_s[(p * 32 + j) * 2 + 1], s1);
        }
        red[(e * 4 + p) * 2] = s0;
        red[(e * 4 + p) * 2 + 1] = s1;
    }
    __syncthreads();
    if (t < 64) {
        float o0 = b2_s[0], o1 = b2_s[1];
#pragma unroll
        for (int p = 0; p < 4; ++p) {
            o0 += red[(t * 4 + p) * 2];
            o1 += red[(t * 4 + p) * 2 + 1];
        }
        out[(e0 + t) * 2] = o0;
        out[(e0 + t) * 2 + 1] = o1;
    }
}

// ---------------------------------------------------------------------------
extern "C" void kernel_launch(void* const* d_in, const int* in_sizes, int n_in,
                              void* d_out, int out_size, void* d_ws, size_t ws_size,
                              hipStream_t stream) {
    (void)in_sizes; (void)n_in; (void)out_size; (void)ws_size;
    const float* x    = (const float*)d_in[0];
    const unsigned* eidx = (const unsigned*)d_in[1];
    const float* ea   = (const float*)d_in[2];
    const float* e1w  = (const float*)d_in[3];
    const float* e1b  = (const float*)d_in[4];
    const float* m1w1 = (const float*)d_in[5];
    const float* m1b1 = (const float*)d_in[6];
    const float* m1w2 = (const float*)d_in[7];
    const float* m1b2 = (const float*)d_in[8];
    const float* e2w  = (const float*)d_in[9];
    const float* e2b  = (const float*)d_in[10];
    const float* m2w1 = (const float*)d_in[11];
    const float* m2b1 = (const float*)d_in[12];
    const float* m2w2 = (const float*)d_in[13];
    const float* m2b2 = (const float*)d_in[14];
    const float* emw1 = (const float*)d_in[15];
    const float* emb1 = (const float*)d_in[16];
    const float* emw2 = (const float*)d_in[17];
    const float* emb2 = (const float*)d_in[18];
    float* out = (float*)d_out;

    char* ws = (char*)d_ws;
    float* yagg = (float*)(ws + 0);                      // 51.2 MB (reused as agg2)
    float* r1   = (float*)(ws + 51200000);               // 51.2 MB
    unsigned short* r2   = (unsigned short*)(ws + 102400000);  // 25.6 MB
    unsigned short* W1t  = (unsigned short*)(ws + 128000000);  // 106,496 B
    unsigned short* W2t  = (unsigned short*)(ws + 128106496);  // 32,768 B
    unsigned short* V1t  = (unsigned short*)(ws + 128139264);  // 32,768 B
    unsigned short* V2t  = (unsigned short*)(ws + 128172032);  // 32,768 B
    unsigned short* EW1t = (unsigned short*)(ws + 128204800);  // 65,536 B
    int* s32 = (int*)(ws + 128270336);                   // 2.4 MB
    int* d32 = (int*)(ws + 130670336);                   // 2.4 MB

    hipMemsetAsync(yagg, 0, (size_t)N_NODES * HID * 4, stream);
    k_decode<<<2344, 256, 0, stream>>>(eidx, s32, d32);
    k_prep<<<528, 256, 0, stream>>>(m1w1, m1w2, m2w1, m2w2, emw1, W1t, W2t, V1t, V2t, EW1t);
    k_edge1<<<N_EDGES / 64, 256, 0, stream>>>(x, s32, d32, ea, e1w, e1b, W1t, yagg);
    k_node1<<<(N_NODES + 63) / 64, 256, 0, stream>>>(x, yagg, W1t, W2t, m1b1, m1b2, r1);
    hipMemsetAsync(yagg, 0, (size_t)N_NODES * HID * 4, stream);
    k_edge2<<<N_EDGES / 4, 256, 0, stream>>>(r1, s32, d32, ea, e2w, e2b, yagg);
    k_node2<<<(N_NODES + 63) / 64, 256, 0, stream>>>(r1, yagg, V1t, V2t, m2b1, m2b2, r2);
    k_head<<<N_EDGES / 64, 256, 0, stream>>>(r2, s32, d32, ea, EW1t, emw1, emb1, emw2, emb2, out);
}

// Round 5
// 1107.177 us; speedup vs baseline: 1.1457x; 1.1457x over previous
//
#include <hip/hip_runtime.h>

// ---------------------------------------------------------------------------
// GINE edge model: conv1(387->128 via linearity trick) -> conv2(128) -> edge head
// f32 in/out; bf16 MFMA (16x16x32) with f32 accumulation for the big GEMMs.
// Round 4 (resubmit): dst-sorted edge processing + block-segmented reduction
// (kills the 300MB atomic RMW write-through that dominated k_edge1/k_edge2).
// ---------------------------------------------------------------------------

using f32x4 = __attribute__((ext_vector_type(4))) float;
using s16x8 = __attribute__((ext_vector_type(8))) short;

#define N_NODES 100000
#define N_EDGES 600000
#define NODE_IN 387
#define KPAD    416   // 13 * 32
#define HID     128
#define NB_SCAN 391   // ceil(100000/256)

__device__ __forceinline__ unsigned short f2bf(float f) {
    unsigned u = __float_as_uint(f);
    u += 0x7FFFu + ((u >> 16) & 1u);   // RNE
    return (unsigned short)(u >> 16);
}

// --------------------------- edge_index decode -----------------------------
__global__ __launch_bounds__(256) void k_decode(const unsigned* __restrict__ w,
                                                int* __restrict__ s32,
                                                int* __restrict__ d32) {
    __shared__ unsigned long long bs[4];
    __shared__ int is64_s;
    const int t = threadIdx.x;
    unsigned any = 0;
    for (int i = 1 + 2 * t; i < 2048; i += 512) any |= w[i];
    unsigned long long b = __ballot(any != 0);
    if ((t & 63) == 0) bs[t >> 6] = b;
    __syncthreads();
    if (t == 0) is64_s = ((bs[0] | bs[1] | bs[2] | bs[3]) == 0ULL) ? 1 : 0;
    __syncthreads();
    const int is64 = is64_s;
    const int e = blockIdx.x * 256 + t;
    if (e < N_EDGES) {
        if (is64) {
            s32[e] = (int)w[2 * e];
            d32[e] = (int)w[2 * N_EDGES + 2 * e];
        } else {
            s32[e] = (int)w[e];
            d32[e] = (int)w[N_EDGES + e];
        }
    }
}

// ------------------------ weight transpose + bf16 --------------------------
__global__ __launch_bounds__(256) void k_prep(const float* __restrict__ w1,
                                              const float* __restrict__ w2,
                                              const float* __restrict__ v1,
                                              const float* __restrict__ v2,
                                              const float* __restrict__ ew1,
                                              unsigned short* __restrict__ W1t,
                                              unsigned short* __restrict__ W2t,
                                              unsigned short* __restrict__ V1t,
                                              unsigned short* __restrict__ V2t,
                                              unsigned short* __restrict__ EW1t) {
    int i = blockIdx.x * 256 + threadIdx.x;
    if (i < 128 * KPAD) {
        int c = i / KPAD, k = i - c * KPAD;
        W1t[i] = (k < NODE_IN) ? f2bf(w1[k * HID + c]) : (unsigned short)0;
        return;
    }
    i -= 128 * KPAD;
    if (i < 16384) { int c = i >> 7, k = i & 127; W2t[i] = f2bf(w2[k * HID + c]); return; }
    i -= 16384;
    if (i < 16384) { int c = i >> 7, k = i & 127; V1t[i] = f2bf(v1[k * HID + c]); return; }
    i -= 16384;
    if (i < 16384) { int c = i >> 7, k = i & 127; V2t[i] = f2bf(v2[k * HID + c]); return; }
    i -= 16384;
    if (i < 32768) { int c = i >> 8, k = i & 255; EW1t[i] = f2bf(ew1[k * HID + c]); return; }
}

// ------------------------- counting sort by dst ----------------------------
__global__ __launch_bounds__(256) void k_hist(const int* __restrict__ d32,
                                              int* __restrict__ cnt) {
    const int e = blockIdx.x * 256 + threadIdx.x;
    if (e < N_EDGES) atomicAdd(&cnt[d32[e]], 1);
}

__global__ __launch_bounds__(256) void k_scanA(const int* __restrict__ cnt,
                                               int* __restrict__ bsum) {
    __shared__ int wt[4];
    const int t = threadIdx.x;
    const int i = blockIdx.x * 256 + t;
    int v = (i < N_NODES) ? cnt[i] : 0;
#pragma unroll
    for (int off = 32; off; off >>= 1) v += __shfl_down(v, off);
    if ((t & 63) == 0) wt[t >> 6] = v;
    __syncthreads();
    if (t == 0) bsum[blockIdx.x] = wt[0] + wt[1] + wt[2] + wt[3];
}

// cnt[i] <- exclusive prefix sum (in place); doubles as scatter cursor.
__global__ __launch_bounds__(256) void k_scanC(int* __restrict__ cnt,
                                               const int* __restrict__ bsum) {
    __shared__ int wt[4];
    __shared__ int wt2[4];
    __shared__ int sh_bofs;
    const int t = threadIdx.x, b = blockIdx.x;
    // block offset = sum of bsum[0..b-1]
    int accp = 0;
    for (int i = t; i < NB_SCAN; i += 256) if (i < b) accp += bsum[i];
#pragma unroll
    for (int off = 32; off; off >>= 1) accp += __shfl_down(accp, off);
    if ((t & 63) == 0) wt[t >> 6] = accp;
    __syncthreads();
    if (t == 0) sh_bofs = wt[0] + wt[1] + wt[2] + wt[3];
    // in-block inclusive scan of cnt
    const int i = b * 256 + t;
    const int v = (i < N_NODES) ? cnt[i] : 0;
    int inc = v;
    const int lane = t & 63;
#pragma unroll
    for (int off = 1; off < 64; off <<= 1) {
        int u = __shfl_up(inc, off);
        if (lane >= off) inc += u;
    }
    if (lane == 63) wt2[t >> 6] = inc;
    __syncthreads();
    int wbase = 0;
    for (int wI = 0; wI < (t >> 6); ++wI) wbase += wt2[wI];
    if (i < N_NODES) cnt[i] = sh_bofs + wbase + inc - v;
}

__global__ __launch_bounds__(256) void k_scatter(const int* __restrict__ s32,
                                                 const int* __restrict__ d32,
                                                 int* __restrict__ cur,
                                                 int* __restrict__ ss2,
                                                 int* __restrict__ ds2,
                                                 int* __restrict__ ep) {
    const int e = blockIdx.x * 256 + threadIdx.x;
    if (e < N_EDGES) {
        const int d = d32[e];
        const int pos = atomicAdd(&cur[d], 1);
        ss2[pos] = s32[e];
        ds2[pos] = d;
        ep[pos]  = e;
    }
}

// Full B-tile staging: 128 cols x 32 k bf16 -> 256 threads x 16 shorts.
#define STAGE_B(dst, srcbase, stride_) do {                                   \
    const int col_ = t >> 1, h_ = t & 1;                                      \
    *(s16x8*)&(dst)[col_ * 40 + h_ * 16] =                                    \
        *(const s16x8*)&(srcbase)[col_ * (stride_) + h_ * 16];                \
    *(s16x8*)&(dst)[col_ * 40 + h_ * 16 + 8] =                                \
        *(const s16x8*)&(srcbase)[col_ * (stride_) + h_ * 16 + 8];            \
} while (0)

// ----------------- conv1: per-edge msg GEMM + segmented reduce -------------
// Edges arrive dst-sorted; epilogue does per-column run-length reduction in
// LDS, one coalesced atomic per (run, column) instead of per (row, column).
__global__ __launch_bounds__(256) void k_edge1(const float* __restrict__ x,
                                               const int* __restrict__ ss2,
                                               const int* __restrict__ ds2,
                                               const int* __restrict__ ep,
                                               const float* __restrict__ ea,
                                               const float* __restrict__ e1w,
                                               const float* __restrict__ e1b,
                                               const unsigned short* __restrict__ W1t,
                                               float* __restrict__ yagg) {
    __shared__ __align__(16) char pool[31488];
    unsigned short* Asm = (unsigned short*)(pool);            // 64*40*2   = 5120
    unsigned short* Bsm = (unsigned short*)(pool + 5120);     // 128*40*2  = 10240
    float* e1w_s = (float*)(pool + 15360);                    // 7*416*4   = 11648
    float* e1b_s = (float*)(pool + 27008);                    // 416*4     = 1664
    float* ea_s  = (float*)(pool + 28672);                    // 64*8*4    = 2048
    int* ss_s    = (int*)(pool + 30720);                      // 256
    int* dst_s   = (int*)(pool + 30976);                      // 256
    int* ep_s    = (int*)(pool + 31232);                      // 256
    float* Csm   = (float*)(pool);                            // epilogue alias: 32*129*4 = 16512

    const int t = threadIdx.x;
    const int e0 = blockIdx.x * 64;

    if (t < 64) ss_s[t] = ss2[e0 + t];
    else if (t < 128) dst_s[t - 64] = ds2[e0 + (t - 64)];
    else if (t < 192) ep_s[t - 128] = ep[e0 + (t - 128)];
    for (int i = t; i < 7 * KPAD; i += 256) {
        int q = i / KPAD, k = i - q * KPAD;
        e1w_s[i] = (k < NODE_IN) ? e1w[q * NODE_IN + k] : 0.f;
    }
    for (int i = t; i < KPAD; i += 256) e1b_s[i] = (i < NODE_IN) ? e1b[i] : 0.f;
    __syncthreads();
    for (int i = t; i < 64 * 7; i += 256) {
        int r = i / 7, q = i - r * 7;
        ea_s[r * 8 + q] = ea[ep_s[r] * 7 + q];
    }
    __syncthreads();

    const int lane = t & 63, wid = t >> 6;
    const int wr = wid >> 1, wc = wid & 1;
    const int r = t >> 2, kc = (t & 3) * 8;
    const int srow = ss_s[r];
    float eav[7];
#pragma unroll
    for (int q = 0; q < 7; ++q) eav[q] = ea_s[r * 8 + q];

    f32x4 acc[2][4];
    const f32x4 zero = {0.f, 0.f, 0.f, 0.f};
#pragma unroll
    for (int mi = 0; mi < 2; ++mi)
#pragma unroll
        for (int ni = 0; ni < 4; ++ni) acc[mi][ni] = zero;

    for (int ks = 0; ks < 13; ++ks) {
        {   // A stage: msg tile 64x32 bf16
            const int kb = ks * 32 + kc;
            s16x8 v;
#pragma unroll
            for (int j = 0; j < 8; ++j) {
                const int k = kb + j;
                float val = 0.f;
                if (k < NODE_IN) {
                    float le = e1b_s[k];
#pragma unroll
                    for (int q = 0; q < 7; ++q) le = fmaf(eav[q], e1w_s[q * KPAD + k], le);
                    val = x[srow * NODE_IN + k] + le;
                    val = fmaxf(val, 0.f);
                }
                v[j] = (short)f2bf(val);
            }
            *(s16x8*)&Asm[r * 40 + kc] = v;
        }
        STAGE_B(Bsm, &W1t[ks * 32], KPAD);
        __syncthreads();
        const int koff = (lane >> 4) * 8;
        const int rA = lane & 15;
        s16x8 a0 = *(const s16x8*)&Asm[(wr * 32 + rA) * 40 + koff];
        s16x8 a1 = *(const s16x8*)&Asm[(wr * 32 + 16 + rA) * 40 + koff];
#pragma unroll
        for (int ni = 0; ni < 4; ++ni) {
            s16x8 b = *(const s16x8*)&Bsm[(wc * 64 + ni * 16 + rA) * 40 + koff];
            acc[0][ni] = __builtin_amdgcn_mfma_f32_16x16x32_bf16(a0, b, acc[0][ni], 0, 0, 0);
            acc[1][ni] = __builtin_amdgcn_mfma_f32_16x16x32_bf16(a1, b, acc[1][ni], 0, 0, 0);
        }
        __syncthreads();
    }
    // segmented-reduce epilogue: two passes of 32 rows via LDS
    const int g = lane >> 4;
    const int cb = wc * 64 + (lane & 15);
#pragma unroll
    for (int p = 0; p < 2; ++p) {
        if (wr == p) {
#pragma unroll
            for (int mi = 0; mi < 2; ++mi)
#pragma unroll
                for (int reg = 0; reg < 4; ++reg) {
                    const int row = mi * 16 + g * 4 + reg;   // 0..31
#pragma unroll
                    for (int ni = 0; ni < 4; ++ni)
                        Csm[row * 129 + cb + ni * 16] = acc[mi][ni][reg];
                }
        }
        __syncthreads();
        if (t < 128) {
            const int base = p * 32;
            float s = 0.f;
            int prev = dst_s[base];
            for (int rr = 0; rr < 32; ++rr) {
                const int d = dst_s[base + rr];
                const float v = Csm[rr * 129 + t];
                if (d != prev) { atomicAdd(&yagg[prev * HID + t], s); s = 0.f; prev = d; }
                s += v;
            }
            atomicAdd(&yagg[prev * HID + t], s);
        }
        __syncthreads();
    }
}

// -------------- node MLP1: r1 = relu(relu(x@W1 + yagg + b1)@W2 + b2) -------
__global__ __launch_bounds__(256) void k_node1(const float* __restrict__ x,
                                               const float* __restrict__ yagg,
                                               const unsigned short* __restrict__ W1t,
                                               const unsigned short* __restrict__ W2t,
                                               const float* __restrict__ b1,
                                               const float* __restrict__ b2,
                                               float* __restrict__ r1) {
    __shared__ __align__(16) unsigned short Asm[64 * 40];
    __shared__ __align__(16) unsigned short Bsm[128 * 40];
    __shared__ __align__(16) unsigned short Hsm[64 * 136];
    const int t = threadIdx.x;
    const int i0 = blockIdx.x * 64;
    const int lane = t & 63, wid = t >> 6, wr = wid >> 1, wc = wid & 1;
    const int r = t >> 2, kc = (t & 3) * 8;
    const int rg = i0 + r;
    const bool rvalid = rg < N_NODES;

    f32x4 acc[2][4];
    const f32x4 zero = {0.f, 0.f, 0.f, 0.f};
#pragma unroll
    for (int mi = 0; mi < 2; ++mi)
#pragma unroll
        for (int ni = 0; ni < 4; ++ni) acc[mi][ni] = zero;

    for (int ks = 0; ks < 13; ++ks) {
        {
            const int kb = ks * 32 + kc;
            s16x8 v;
#pragma unroll
            for (int j = 0; j < 8; ++j) {
                const int k = kb + j;
                float val = (rvalid && k < NODE_IN) ? x[rg * NODE_IN + k] : 0.f;
                v[j] = (short)f2bf(val);
            }
            *(s16x8*)&Asm[r * 40 + kc] = v;
        }
        STAGE_B(Bsm, &W1t[ks * 32], KPAD);
        __syncthreads();
        const int koff = (lane >> 4) * 8;
        const int rA = lane & 15;
        s16x8 a0 = *(const s16x8*)&Asm[(wr * 32 + rA) * 40 + koff];
        s16x8 a1 = *(const s16x8*)&Asm[(wr * 32 + 16 + rA) * 40 + koff];
#pragma unroll
        for (int ni = 0; ni < 4; ++ni) {
            s16x8 b = *(const s16x8*)&Bsm[(wc * 64 + ni * 16 + rA) * 40 + koff];
            acc[0][ni] = __builtin_amdgcn_mfma_f32_16x16x32_bf16(a0, b, acc[0][ni], 0, 0, 0);
            acc[1][ni] = __builtin_amdgcn_mfma_f32_16x16x32_bf16(a1, b, acc[1][ni], 0, 0, 0);
        }
        __syncthreads();
    }
    const int jb = wc * 64 + (lane & 15);
#pragma unroll
    for (int mi = 0; mi < 2; ++mi) {
#pragma unroll
        for (int reg = 0; reg < 4; ++reg) {
            const int rloc = wr * 32 + mi * 16 + (lane >> 4) * 4 + reg;
            const int rowg = i0 + rloc;
#pragma unroll
            for (int ni = 0; ni < 4; ++ni) {
                const int j = jb + ni * 16;
                float v = acc[mi][ni][reg];
                if (rowg < N_NODES) {
                    v += yagg[rowg * HID + j] + b1[j];
                    v = fmaxf(v, 0.f);
                } else v = 0.f;
                Hsm[rloc * 136 + j] = f2bf(v);
            }
        }
    }
    __syncthreads();
    f32x4 acc2[2][4];
#pragma unroll
    for (int mi = 0; mi < 2; ++mi)
#pragma unroll
        for (int ni = 0; ni < 4; ++ni) acc2[mi][ni] = zero;

    for (int ks = 0; ks < 4; ++ks) {
        STAGE_B(Bsm, &W2t[ks * 32], HID);
        __syncthreads();
        const int koff = (lane >> 4) * 8;
        const int rA = lane & 15;
        s16x8 a0 = *(const s16x8*)&Hsm[(wr * 32 + rA) * 136 + ks * 32 + koff];
        s16x8 a1 = *(const s16x8*)&Hsm[(wr * 32 + 16 + rA) * 136 + ks * 32 + koff];
#pragma unroll
        for (int ni = 0; ni < 4; ++ni) {
            s16x8 b = *(const s16x8*)&Bsm[(wc * 64 + ni * 16 + rA) * 40 + koff];
            acc2[0][ni] = __builtin_amdgcn_mfma_f32_16x16x32_bf16(a0, b, acc2[0][ni], 0, 0, 0);
            acc2[1][ni] = __builtin_amdgcn_mfma_f32_16x16x32_bf16(a1, b, acc2[1][ni], 0, 0, 0);
        }
        __syncthreads();
    }
#pragma unroll
    for (int mi = 0; mi < 2; ++mi) {
#pragma unroll
        for (int reg = 0; reg < 4; ++reg) {
            const int rloc = wr * 32 + mi * 16 + (lane >> 4) * 4 + reg;
            const int rowg = i0 + rloc;
            if (rowg < N_NODES) {
#pragma unroll
                for (int ni = 0; ni < 4; ++ni) {
                    const int j = jb + ni * 16;
                    float v = acc2[mi][ni][reg] + b2[j];
                    r1[rowg * HID + j] = fmaxf(v, 0.f);
                }
            }
        }
    }
}

// ---- conv2 message pass (sorted): agg2[dst] += relu(r1[src]+ea@e2w+b) -----
__global__ __launch_bounds__(256) void k_edge2(const float* __restrict__ r1,
                                               const int* __restrict__ ss2,
                                               const int* __restrict__ ds2,
                                               const int* __restrict__ ep,
                                               const float* __restrict__ ea,
                                               const float* __restrict__ e2w,
                                               const float* __restrict__ e2b,
                                               float* __restrict__ agg2) {
    __shared__ float w_s[7 * HID];
    __shared__ float b_s[HID];
    __shared__ float Csm[64 * 129];
    __shared__ int ss_s[64];
    __shared__ int ds_s[64];
    __shared__ int pe_s[64];
    const int t = threadIdx.x;
    const int e0 = blockIdx.x * 64;
    for (int i = t; i < 7 * HID; i += 256) w_s[i] = e2w[i];
    if (t < HID) b_s[t] = e2b[t];
    if (t < 64) ss_s[t] = ss2[e0 + t];
    else if (t < 128) ds_s[t - 64] = ds2[e0 + (t - 64)];
    else if (t < 192) pe_s[t - 128] = ep[e0 + (t - 128)];
    __syncthreads();

    const int r = t >> 2, c0 = (t & 3) * 32;
    const int s = ss_s[r];
    const int pe = pe_s[r];
    float eav[7];
#pragma unroll
    for (int q = 0; q < 7; ++q) eav[q] = ea[pe * 7 + q];
    const f32x4* rp = (const f32x4*)&r1[s * HID + c0];
#pragma unroll
    for (int u = 0; u < 8; ++u) {
        f32x4 v4 = rp[u];
#pragma unroll
        for (int j = 0; j < 4; ++j) {
            const int c = c0 + u * 4 + j;
            float v = v4[j] + b_s[c];
#pragma unroll
            for (int q = 0; q < 7; ++q) v = fmaf(eav[q], w_s[q * HID + c], v);
            Csm[r * 129 + c] = fmaxf(v, 0.f);
        }
    }
    __syncthreads();
    if (t < 128) {
        float ssum = 0.f;
        int prev = ds_s[0];
        for (int rr = 0; rr < 64; ++rr) {
            const int d = ds_s[rr];
            const float v = Csm[rr * 129 + t];
            if (d != prev) { atomicAdd(&agg2[prev * HID + t], ssum); ssum = 0.f; prev = d; }
            ssum += v;
        }
        atomicAdd(&agg2[prev * HID + t], ssum);
    }
}

// -------- node MLP2: r2 = bf16(relu(relu((r1+agg2)@V1 + b1)@V2 + b2)) ------
__global__ __launch_bounds__(256) void k_node2(const float* __restrict__ r1,
                                               const float* __restrict__ agg2,
                                               const unsigned short* __restrict__ V1t,
                                               const unsigned short* __restrict__ V2t,
                                               const float* __restrict__ b1,
                                               const float* __restrict__ b2,
                                               unsigned short* __restrict__ r2) {
    __shared__ __align__(16) unsigned short Asm[64 * 40];
    __shared__ __align__(16) unsigned short Bsm[128 * 40];
    __shared__ __align__(16) unsigned short Hsm[64 * 136];
    const int t = threadIdx.x;
    const int i0 = blockIdx.x * 64;
    const int lane = t & 63, wid = t >> 6, wr = wid >> 1, wc = wid & 1;
    const int r = t >> 2, kc = (t & 3) * 8;
    const int rg = i0 + r;
    const bool rvalid = rg < N_NODES;

    f32x4 acc[2][4];
    const f32x4 zero = {0.f, 0.f, 0.f, 0.f};
#pragma unroll
    for (int mi = 0; mi < 2; ++mi)
#pragma unroll
        for (int ni = 0; ni < 4; ++ni) acc[mi][ni] = zero;

    for (int ks = 0; ks < 4; ++ks) {
        {
            const int kb = ks * 32 + kc;
            s16x8 v;
            if (rvalid) {
                const f32x4* pa = (const f32x4*)&r1[rg * HID + kb];
                const f32x4* pb = (const f32x4*)&agg2[rg * HID + kb];
                f32x4 u0 = pa[0], u1 = pa[1], w0 = pb[0], w1 = pb[1];
#pragma unroll
                for (int j = 0; j < 4; ++j) v[j] = (short)f2bf(u0[j] + w0[j]);
#pragma unroll
                for (int j = 0; j < 4; ++j) v[4 + j] = (short)f2bf(u1[j] + w1[j]);
            } else {
#pragma unroll
                for (int j = 0; j < 8; ++j) v[j] = 0;
            }
            *(s16x8*)&Asm[r * 40 + kc] = v;
        }
        STAGE_B(Bsm, &V1t[ks * 32], HID);
        __syncthreads();
        const int koff = (lane >> 4) * 8;
        const int rA = lane & 15;
        s16x8 a0 = *(const s16x8*)&Asm[(wr * 32 + rA) * 40 + koff];
        s16x8 a1 = *(const s16x8*)&Asm[(wr * 32 + 16 + rA) * 40 + koff];
#pragma unroll
        for (int ni = 0; ni < 4; ++ni) {
            s16x8 b = *(const s16x8*)&Bsm[(wc * 64 + ni * 16 + rA) * 40 + koff];
            acc[0][ni] = __builtin_amdgcn_mfma_f32_16x16x32_bf16(a0, b, acc[0][ni], 0, 0, 0);
            acc[1][ni] = __builtin_amdgcn_mfma_f32_16x16x32_bf16(a1, b, acc[1][ni], 0, 0, 0);
        }
        __syncthreads();
    }
    const int jb = wc * 64 + (lane & 15);
#pragma unroll
    for (int mi = 0; mi < 2; ++mi) {
#pragma unroll
        for (int reg = 0; reg < 4; ++reg) {
            const int rloc = wr * 32 + mi * 16 + (lane >> 4) * 4 + reg;
            const int rowg = i0 + rloc;
#pragma unroll
            for (int ni = 0; ni < 4; ++ni) {
                const int j = jb + ni * 16;
                float v = acc[mi][ni][reg];
                if (rowg < N_NODES) {
                    v += b1[j];
                    v = fmaxf(v, 0.f);
                } else v = 0.f;
                Hsm[rloc * 136 + j] = f2bf(v);
            }
        }
    }
    __syncthreads();
    f32x4 acc2[2][4];
#pragma unroll
    for (int mi = 0; mi < 2; ++mi)
#pragma unroll
        for (int ni = 0; ni < 4; ++ni) acc2[mi][ni] = zero;

    for (int ks = 0; ks < 4; ++ks) {
        STAGE_B(Bsm, &V2t[ks * 32], HID);
        __syncthreads();
        const int koff = (lane >> 4) * 8;
        const int rA = lane & 15;
        s16x8 a0 = *(const s16x8*)&Hsm[(wr * 32 + rA) * 136 + ks * 32 + koff];
        s16x8 a1 = *(const s16x8*)&Hsm[(wr * 32 + 16 + rA) * 136 + ks * 32 + koff];
#pragma unroll
        for (int ni = 0; ni < 4; ++ni) {
            s16x8 b = *(const s16x8*)&Bsm[(wc * 64 + ni * 16 + rA) * 40 + koff];
            acc2[0][ni] = __builtin_amdgcn_mfma_f32_16x16x32_bf16(a0, b, acc2[0][ni], 0, 0, 0);
            acc2[1][ni] = __builtin_amdgcn_mfma_f32_16x16x32_bf16(a1, b, acc2[1][ni], 0, 0, 0);
        }
        __syncthreads();
    }
#pragma unroll
    for (int mi = 0; mi < 2; ++mi) {
#pragma unroll
        for (int reg = 0; reg < 4; ++reg) {
            const int rloc = wr * 32 + mi * 16 + (lane >> 4) * 4 + reg;
            const int rowg = i0 + rloc;
            if (rowg < N_NODES) {
#pragma unroll
                for (int ni = 0; ni < 4; ++ni) {
                    const int j = jb + ni * 16;
                    float v = acc2[mi][ni][reg] + b2[j];
                    r2[rowg * HID + j] = f2bf(fmaxf(v, 0.f));
                }
            }
        }
    }
}

// ------- edge head: out = relu([r2_s|r2_d|ea] @ em_w1 + b1) @ em_w2 + b2 ---
__global__ __launch_bounds__(256) void k_head(const unsigned short* __restrict__ r2,
                                              const int* __restrict__ srcp,
                                              const int* __restrict__ dstp,
                                              const float* __restrict__ ea,
                                              const unsigned short* __restrict__ EW1t,
                                              const float* __restrict__ emw1,
                                              const float* __restrict__ emb1,
                                              const float* __restrict__ emw2,
                                              const float* __restrict__ emb2,
                                              float* __restrict__ out) {
    __shared__ __align__(16) unsigned short Asm[64 * 40];
    __shared__ __align__(16) unsigned short Bsm[128 * 40];
    __shared__ float Hsm[64 * 129];
    __shared__ float ew_ea[7 * HID];
    __shared__ float eb1_s[HID];
    __shared__ float w2_s[256];
    __shared__ float b2_s[2];
    __shared__ float ea_s[64 * 8];
    __shared__ int src_s[64];
    __shared__ int dst_s[64];
    __shared__ float red[512];
    const int t = threadIdx.x;
    const int e0 = blockIdx.x * 64;

    for (int i = t; i < 7 * HID; i += 256) ew_ea[i] = emw1[256 * HID + i];
    if (t < HID) eb1_s[t] = emb1[t];
    if (t < 256) w2_s[t] = emw2[t];
    if (t < 2) b2_s[t] = emb2[t];
    for (int i = t; i < 64 * 7; i += 256) {
        int r = i / 7, q = i - r * 7;
        ea_s[r * 8 + q] = ea[(e0 + r) * 7 + q];
    }
    if (t < 64) src_s[t] = srcp[e0 + t];
    else if (t < 128) dst_s[t - 64] = dstp[e0 + (t - 64)];
    __syncthreads();

    const int lane = t & 63, wid = t >> 6, wr = wid >> 1, wc = wid & 1;
    const int r = t >> 2, kc = (t & 3) * 8;

    f32x4 acc[2][4];
    const f32x4 zero = {0.f, 0.f, 0.f, 0.f};
#pragma unroll
    for (int mi = 0; mi < 2; ++mi)
#pragma unroll
        for (int ni = 0; ni < 4; ++ni) acc[mi][ni] = zero;

    for (int ks = 0; ks < 8; ++ks) {
        {
            const int k = ks * 32 + kc;
            const unsigned short* p = (k < HID) ? &r2[src_s[r] * HID + k]
                                                : &r2[dst_s[r] * HID + (k - HID)];
            *(s16x8*)&Asm[r * 40 + kc] = *(const s16x8*)p;
        }
        STAGE_B(Bsm, &EW1t[ks * 32], 256);
        __syncthreads();
        const int koff = (lane >> 4) * 8;
        const int rA = lane & 15;
        s16x8 a0 = *(const s16x8*)&Asm[(wr * 32 + rA) * 40 + koff];
        s16x8 a1 = *(const s16x8*)&Asm[(wr * 32 + 16 + rA) * 40 + koff];
#pragma unroll
        for (int ni = 0; ni < 4; ++ni) {
            s16x8 b = *(const s16x8*)&Bsm[(wc * 64 + ni * 16 + rA) * 40 + koff];
            acc[0][ni] = __builtin_amdgcn_mfma_f32_16x16x32_bf16(a0, b, acc[0][ni], 0, 0, 0);
            acc[1][ni] = __builtin_amdgcn_mfma_f32_16x16x32_bf16(a1, b, acc[1][ni], 0, 0, 0);
        }
        __syncthreads();
    }
    const int jb = wc * 64 + (lane & 15);
#pragma unroll
    for (int mi = 0; mi < 2; ++mi) {
#pragma unroll
        for (int reg = 0; reg < 4; ++reg) {
            const int rloc = wr * 32 + mi * 16 + (lane >> 4) * 4 + reg;
#pragma unroll
            for (int ni = 0; ni < 4; ++ni) {
                const int j = jb + ni * 16;
                float v = acc[mi][ni][reg] + eb1_s[j];
#pragma unroll
                for (int q = 0; q < 7; ++q)
                    v = fmaf(ea_s[rloc * 8 + q], ew_ea[q * HID + j], v);
                Hsm[rloc * 129 + j] = fmaxf(v, 0.f);
            }
        }
    }
    __syncthreads();
    {
        const int e = t & 63, p = t >> 6;
        const float* hb = &Hsm[e * 129 + p * 32];
        float s0 = 0.f, s1 = 0.f;
#pragma unroll
        for (int j = 0; j < 32; ++j) {
            const float h = hb[j];
            s0 = fmaf(h, w2_s[(p * 32 + j) * 2], s0);
            s1 = fmaf(h, w2_s[(p * 32 + j) * 2 + 1], s1);
        }
        red[(e * 4 + p) * 2] = s0;
        red[(e * 4 + p) * 2 + 1] = s1;
    }
    __syncthreads();
    if (t < 64) {
        float o0 = b2_s[0], o1 = b2_s[1];
#pragma unroll
        for (int p = 0; p < 4; ++p) {
            o0 += red[(t * 4 + p) * 2];
            o1 += red[(t * 4 + p) * 2 + 1];
        }
        out[(e0 + t) * 2] = o0;
        out[(e0 + t) * 2 + 1] = o1;
    }
}

// ---------------------------------------------------------------------------
extern "C" void kernel_launch(void* const* d_in, const int* in_sizes, int n_in,
                              void* d_out, int out_size, void* d_ws, size_t ws_size,
                              hipStream_t stream) {
    (void)in_sizes; (void)n_in; (void)out_size; (void)ws_size;
    const float* x    = (const float*)d_in[0];
    const unsigned* eidx = (const unsigned*)d_in[1];
    const float* ea   = (const float*)d_in[2];
    const float* e1w  = (const float*)d_in[3];
    const float* e1b  = (const float*)d_in[4];
    const float* m1w1 = (const float*)d_in[5];
    const float* m1b1 = (const float*)d_in[6];
    const float* m1w2 = (const float*)d_in[7];
    const float* m1b2 = (const float*)d_in[8];
    const float* e2w  = (const float*)d_in[9];
    const float* e2b  = (const float*)d_in[10];
    const float* m2w1 = (const float*)d_in[11];
    const float* m2b1 = (const float*)d_in[12];
    const float* m2w2 = (const float*)d_in[13];
    const float* m2b2 = (const float*)d_in[14];
    const float* emw1 = (const float*)d_in[15];
    const float* emb1 = (const float*)d_in[16];
    const float* emw2 = (const float*)d_in[17];
    const float* emb2 = (const float*)d_in[18];
    float* out = (float*)d_out;

    char* ws = (char*)d_ws;
    float* yagg = (float*)(ws + 0);                            // 51.2 MB (reused as agg2)
    float* r1   = (float*)(ws + 51200000);                     // 51.2 MB
    unsigned short* r2   = (unsigned short*)(ws + 102400000);  // 25.6 MB
    unsigned short* W1t  = (unsigned short*)(ws + 128000000);
    unsigned short* W2t  = (unsigned short*)(ws + 128106496);
    unsigned short* V1t  = (unsigned short*)(ws + 128139264);
    unsigned short* V2t  = (unsigned short*)(ws + 128172032);
    unsigned short* EW1t = (unsigned short*)(ws + 128204800);  // ends 128270336
    int* s32  = (int*)(ws + 128270336);                        // 2.4 MB
    int* d32  = (int*)(ws + 130670336);                        // 2.4 MB
    int* ss2  = (int*)(ws + 133070336);                        // 2.4 MB (dst-sorted src)
    int* ds2  = (int*)(ws + 135470336);                        // 2.4 MB (dst-sorted dst)
    int* ep   = (int*)(ws + 137870336);                        // 2.4 MB (orig edge id)
    int* cnt  = (int*)(ws + 140270336);                        // 400 KB (hist -> cursor)
    int* bsum = (int*)(ws + 140670720);                        // 4 KB

    hipMemsetAsync(yagg, 0, (size_t)N_NODES * HID * 4, stream);
    hipMemsetAsync(cnt, 0, (size_t)N_NODES * 4, stream);
    k_decode<<<2344, 256, 0, stream>>>(eidx, s32, d32);
    k_prep<<<528, 256, 0, stream>>>(m1w1, m1w2, m2w1, m2w2, emw1, W1t, W2t, V1t, V2t, EW1t);
    k_hist<<<2344, 256, 0, stream>>>(d32, cnt);
    k_scanA<<<NB_SCAN, 256, 0, stream>>>(cnt, bsum);
    k_scanC<<<NB_SCAN, 256, 0, stream>>>(cnt, bsum);
    k_scatter<<<2344, 256, 0, stream>>>(s32, d32, cnt, ss2, ds2, ep);
    k_edge1<<<N_EDGES / 64, 256, 0, stream>>>(x, ss2, ds2, ep, ea, e1w, e1b, W1t, yagg);
    k_node1<<<(N_NODES + 63) / 64, 256, 0, stream>>>(x, yagg, W1t, W2t, m1b1, m1b2, r1);
    hipMemsetAsync(yagg, 0, (size_t)N_NODES * HID * 4, stream);
    k_edge2<<<N_EDGES / 64, 256, 0, stream>>>(r1, ss2, ds2, ep, ea, e2w, e2b, yagg);
    k_node2<<<(N_NODES + 63) / 64, 256, 0, stream>>>(r1, yagg, V1t, V2t, m2b1, m2b2, r2);
    k_head<<<N_EDGES / 64, 256, 0, stream>>>(r2, s32, d32, ea, EW1t, emw1, emb1, emw2, emb2, out);
}

// Round 6
// 1076.179 us; speedup vs baseline: 1.1787x; 1.0288x over previous
//
#include <hip/hip_runtime.h>

// ---------------------------------------------------------------------------
// GINE edge model. Round 6: bf16 x/r1 operand compression (gather bytes /2,
// L3-resident working sets), register prefetch in k_edge1, pre-sorted ea.
// ---------------------------------------------------------------------------

using f32x4 = __attribute__((ext_vector_type(4))) float;
using s16x8 = __attribute__((ext_vector_type(8))) short;

#define N_NODES 100000
#define N_EDGES 600000
#define NODE_IN 387
#define KPAD    416   // 13 * 32
#define HID     128
#define NB_SCAN 391   // ceil(100000/256)

__device__ __forceinline__ unsigned short f2bf(float f) {
    unsigned u = __float_as_uint(f);
    u += 0x7FFFu + ((u >> 16) & 1u);   // RNE
    return (unsigned short)(u >> 16);
}
__device__ __forceinline__ float bf2f(short h) {
    return __uint_as_float(((unsigned)(unsigned short)h) << 16);
}

// --------------------------- edge_index decode -----------------------------
__global__ __launch_bounds__(256) void k_decode(const unsigned* __restrict__ w,
                                                int* __restrict__ s32,
                                                int* __restrict__ d32) {
    __shared__ unsigned long long bs[4];
    __shared__ int is64_s;
    const int t = threadIdx.x;
    unsigned any = 0;
    for (int i = 1 + 2 * t; i < 2048; i += 512) any |= w[i];
    unsigned long long b = __ballot(any != 0);
    if ((t & 63) == 0) bs[t >> 6] = b;
    __syncthreads();
    if (t == 0) is64_s = ((bs[0] | bs[1] | bs[2] | bs[3]) == 0ULL) ? 1 : 0;
    __syncthreads();
    const int is64 = is64_s;
    const int e = blockIdx.x * 256 + t;
    if (e < N_EDGES) {
        if (is64) {
            s32[e] = (int)w[2 * e];
            d32[e] = (int)w[2 * N_EDGES + 2 * e];
        } else {
            s32[e] = (int)w[e];
            d32[e] = (int)w[N_EDGES + e];
        }
    }
}

// ------------------------ weight transpose + bf16 --------------------------
__global__ __launch_bounds__(256) void k_prep(const float* __restrict__ w1,
                                              const float* __restrict__ w2,
                                              const float* __restrict__ v1,
                                              const float* __restrict__ v2,
                                              const float* __restrict__ ew1,
                                              unsigned short* __restrict__ W1t,
                                              unsigned short* __restrict__ W2t,
                                              unsigned short* __restrict__ V1t,
                                              unsigned short* __restrict__ V2t,
                                              unsigned short* __restrict__ EW1t) {
    int i = blockIdx.x * 256 + threadIdx.x;
    if (i < 128 * KPAD) {
        int c = i / KPAD, k = i - c * KPAD;
        W1t[i] = (k < NODE_IN) ? f2bf(w1[k * HID + c]) : (unsigned short)0;
        return;
    }
    i -= 128 * KPAD;
    if (i < 16384) { int c = i >> 7, k = i & 127; W2t[i] = f2bf(w2[k * HID + c]); return; }
    i -= 16384;
    if (i < 16384) { int c = i >> 7, k = i & 127; V1t[i] = f2bf(v1[k * HID + c]); return; }
    i -= 16384;
    if (i < 16384) { int c = i >> 7, k = i & 127; V2t[i] = f2bf(v2[k * HID + c]); return; }
    i -= 16384;
    if (i < 32768) { int c = i >> 8, k = i & 255; EW1t[i] = f2bf(ew1[k * HID + c]); return; }
}

// -------------------- x -> bf16, K-padded to 416 ---------------------------
__global__ __launch_bounds__(256) void k_castx(const float* __restrict__ x,
                                               unsigned short* __restrict__ xbf) {
    const int g = blockIdx.x * 256 + threadIdx.x;        // one 8-elem group
    if (g >= N_NODES * 52) return;                        // 416/8 = 52 groups/row
    const int row = g / 52, c0 = (g - row * 52) * 8;
    s16x8 v;
#pragma unroll
    for (int j = 0; j < 8; ++j) {
        const int c = c0 + j;
        v[j] = (c < NODE_IN) ? (short)f2bf(x[row * NODE_IN + c]) : (short)0;
    }
    *(s16x8*)&xbf[row * KPAD + c0] = v;
}

// ------------------------- counting sort by dst ----------------------------
__global__ __launch_bounds__(256) void k_hist(const int* __restrict__ d32,
                                              int* __restrict__ cnt) {
    const int e = blockIdx.x * 256 + threadIdx.x;
    if (e < N_EDGES) atomicAdd(&cnt[d32[e]], 1);
}

__global__ __launch_bounds__(256) void k_scanA(const int* __restrict__ cnt,
                                               int* __restrict__ bsum) {
    __shared__ int wt[4];
    const int t = threadIdx.x;
    const int i = blockIdx.x * 256 + t;
    int v = (i < N_NODES) ? cnt[i] : 0;
#pragma unroll
    for (int off = 32; off; off >>= 1) v += __shfl_down(v, off);
    if ((t & 63) == 0) wt[t >> 6] = v;
    __syncthreads();
    if (t == 0) bsum[blockIdx.x] = wt[0] + wt[1] + wt[2] + wt[3];
}

__global__ __launch_bounds__(256) void k_scanC(int* __restrict__ cnt,
                                               const int* __restrict__ bsum) {
    __shared__ int wt[4];
    __shared__ int wt2[4];
    __shared__ int sh_bofs;
    const int t = threadIdx.x, b = blockIdx.x;
    int accp = 0;
    for (int i = t; i < NB_SCAN; i += 256) if (i < b) accp += bsum[i];
#pragma unroll
    for (int off = 32; off; off >>= 1) accp += __shfl_down(accp, off);
    if ((t & 63) == 0) wt[t >> 6] = accp;
    __syncthreads();
    if (t == 0) sh_bofs = wt[0] + wt[1] + wt[2] + wt[3];
    const int i = b * 256 + t;
    const int v = (i < N_NODES) ? cnt[i] : 0;
    int inc = v;
    const int lane = t & 63;
#pragma unroll
    for (int off = 1; off < 64; off <<= 1) {
        int u = __shfl_up(inc, off);
        if (lane >= off) inc += u;
    }
    if (lane == 63) wt2[t >> 6] = inc;
    __syncthreads();
    int wbase = 0;
    for (int wI = 0; wI < (t >> 6); ++wI) wbase += wt2[wI];
    if (i < N_NODES) cnt[i] = sh_bofs + wbase + inc - v;
}

// scatter into dst-sorted order; also pre-gathers ea rows (stride 8 f32).
__global__ __launch_bounds__(256) void k_scatter(const int* __restrict__ s32,
                                                 const int* __restrict__ d32,
                                                 const float* __restrict__ ea,
                                                 int* __restrict__ cur,
                                                 int* __restrict__ ss2,
                                                 int* __restrict__ ds2,
                                                 float* __restrict__ eas) {
    const int e = blockIdx.x * 256 + threadIdx.x;
    if (e < N_EDGES) {
        const int d = d32[e];
        const int pos = atomicAdd(&cur[d], 1);
        ss2[pos] = s32[e];
        ds2[pos] = d;
#pragma unroll
        for (int q = 0; q < 7; ++q) eas[pos * 8 + q] = ea[e * 7 + q];
        eas[pos * 8 + 7] = 0.f;
    }
}

// Full B-tile staging: 128 cols x 32 k bf16 -> 256 threads x 16 shorts.
#define STAGE_B(dst, srcbase, stride_) do {                                   \
    const int col_ = t >> 1, h_ = t & 1;                                      \
    *(s16x8*)&(dst)[col_ * 40 + h_ * 16] =                                    \
        *(const s16x8*)&(srcbase)[col_ * (stride_) + h_ * 16];                \
    *(s16x8*)&(dst)[col_ * 40 + h_ * 16 + 8] =                                \
        *(const s16x8*)&(srcbase)[col_ * (stride_) + h_ * 16 + 8];            \
} while (0)

// ----------------- conv1: per-edge msg GEMM + segmented reduce -------------
__global__ __launch_bounds__(256) void k_edge1(const unsigned short* __restrict__ xbf,
                                               const int* __restrict__ ss2,
                                               const int* __restrict__ ds2,
                                               const float* __restrict__ eas,
                                               const float* __restrict__ e1w,
                                               const float* __restrict__ e1b,
                                               const unsigned short* __restrict__ W1t,
                                               float* __restrict__ yagg) {
    __shared__ __align__(16) char pool[31232];
    unsigned short* Asm = (unsigned short*)(pool);            // 5120
    unsigned short* Bsm = (unsigned short*)(pool + 5120);     // 10240
    float* e1w_s = (float*)(pool + 15360);                    // 11648
    float* e1b_s = (float*)(pool + 27008);                    // 1664
    float* ea_s  = (float*)(pool + 28672);                    // 2048
    int* ss_s    = (int*)(pool + 30720);                      // 256
    int* dst_s   = (int*)(pool + 30976);                      // 256
    float* Csm   = (float*)(pool);                            // epilogue alias 16512

    const int t = threadIdx.x;
    const int e0 = blockIdx.x * 64;

    if (t < 64) ss_s[t] = ss2[e0 + t];
    else if (t < 128) dst_s[t - 64] = ds2[e0 + (t - 64)];
    for (int i = t; i < 7 * KPAD; i += 256) {
        int q = i / KPAD, k = i - q * KPAD;
        e1w_s[i] = (k < NODE_IN) ? e1w[q * NODE_IN + k] : 0.f;
    }
    for (int i = t; i < KPAD; i += 256) e1b_s[i] = (i < NODE_IN) ? e1b[i] : 0.f;
    for (int i = t; i < 512; i += 256) ea_s[i] = eas[e0 * 8 + i];
    __syncthreads();

    const int lane = t & 63, wid = t >> 6;
    const int wr = wid >> 1, wc = wid & 1;
    const int r = t >> 2, kc = (t & 3) * 8;
    const int srow = ss_s[r];
    float eav[7];
#pragma unroll
    for (int q = 0; q < 7; ++q) eav[q] = ea_s[r * 8 + q];

    f32x4 acc[2][4];
    const f32x4 zero = {0.f, 0.f, 0.f, 0.f};
#pragma unroll
    for (int mi = 0; mi < 2; ++mi)
#pragma unroll
        for (int ni = 0; ni < 4; ++ni) acc[mi][ni] = zero;

    // x-tile register prefetch pipeline
    s16x8 xa_n = *(const s16x8*)&xbf[srow * KPAD + kc];
    for (int ks = 0; ks < 13; ++ks) {
        const s16x8 xa = xa_n;
        if (ks < 12) xa_n = *(const s16x8*)&xbf[srow * KPAD + (ks + 1) * 32 + kc];
        {   // A stage: msg tile 64x32 bf16 (branch-free: pads are all zero)
            const int kb = ks * 32 + kc;
            s16x8 v;
#pragma unroll
            for (int j = 0; j < 8; ++j) {
                const int k = kb + j;
                float le = e1b_s[k];
#pragma unroll
                for (int q = 0; q < 7; ++q) le = fmaf(eav[q], e1w_s[q * KPAD + k], le);
                v[j] = (short)f2bf(fmaxf(bf2f(xa[j]) + le, 0.f));
            }
            *(s16x8*)&Asm[r * 40 + kc] = v;
        }
        STAGE_B(Bsm, &W1t[ks * 32], KPAD);
        __syncthreads();
        const int koff = (lane >> 4) * 8;
        const int rA = lane & 15;
        s16x8 a0 = *(const s16x8*)&Asm[(wr * 32 + rA) * 40 + koff];
        s16x8 a1 = *(const s16x8*)&Asm[(wr * 32 + 16 + rA) * 40 + koff];
#pragma unroll
        for (int ni = 0; ni < 4; ++ni) {
            s16x8 b = *(const s16x8*)&Bsm[(wc * 64 + ni * 16 + rA) * 40 + koff];
            acc[0][ni] = __builtin_amdgcn_mfma_f32_16x16x32_bf16(a0, b, acc[0][ni], 0, 0, 0);
            acc[1][ni] = __builtin_amdgcn_mfma_f32_16x16x32_bf16(a1, b, acc[1][ni], 0, 0, 0);
        }
        __syncthreads();
    }
    // segmented-reduce epilogue: two passes of 32 rows via LDS
    const int g = lane >> 4;
    const int cb = wc * 64 + (lane & 15);
#pragma unroll
    for (int p = 0; p < 2; ++p) {
        if (wr == p) {
#pragma unroll
            for (int mi = 0; mi < 2; ++mi)
#pragma unroll
                for (int reg = 0; reg < 4; ++reg) {
                    const int row = mi * 16 + g * 4 + reg;   // 0..31
#pragma unroll
                    for (int ni = 0; ni < 4; ++ni)
                        Csm[row * 129 + cb + ni * 16] = acc[mi][ni][reg];
                }
        }
        __syncthreads();
        if (t < 128) {
            const int base = p * 32;
            float s = 0.f;
            int prev = dst_s[base];
            for (int rr = 0; rr < 32; ++rr) {
                const int d = dst_s[base + rr];
                const float v = Csm[rr * 129 + t];
                if (d != prev) { atomicAdd(&yagg[prev * HID + t], s); s = 0.f; prev = d; }
                s += v;
            }
            atomicAdd(&yagg[prev * HID + t], s);
        }
        __syncthreads();
    }
}

// -------------- node MLP1: r1b = bf16(relu(relu(x@W1+yagg+b1)@W2+b2)) ------
__global__ __launch_bounds__(256) void k_node1(const unsigned short* __restrict__ xbf,
                                               const float* __restrict__ yagg,
                                               const unsigned short* __restrict__ W1t,
                                               const unsigned short* __restrict__ W2t,
                                               const float* __restrict__ b1,
                                               const float* __restrict__ b2,
                                               unsigned short* __restrict__ r1b) {
    __shared__ __align__(16) unsigned short Asm[64 * 40];
    __shared__ __align__(16) unsigned short Bsm[128 * 40];
    __shared__ __align__(16) unsigned short Hsm[64 * 136];
    const int t = threadIdx.x;
    const int i0 = blockIdx.x * 64;
    const int lane = t & 63, wid = t >> 6, wr = wid >> 1, wc = wid & 1;
    const int r = t >> 2, kc = (t & 3) * 8;
    const int rg = i0 + r;
    const bool rvalid = rg < N_NODES;

    f32x4 acc[2][4];
    const f32x4 zero = {0.f, 0.f, 0.f, 0.f};
#pragma unroll
    for (int mi = 0; mi < 2; ++mi)
#pragma unroll
        for (int ni = 0; ni < 4; ++ni) acc[mi][ni] = zero;

    for (int ks = 0; ks < 13; ++ks) {
        {   // A stage: direct bf16 copy from padded xbf
            s16x8 v;
            if (rvalid) v = *(const s16x8*)&xbf[rg * KPAD + ks * 32 + kc];
            else {
#pragma unroll
                for (int j = 0; j < 8; ++j) v[j] = 0;
            }
            *(s16x8*)&Asm[r * 40 + kc] = v;
        }
        STAGE_B(Bsm, &W1t[ks * 32], KPAD);
        __syncthreads();
        const int koff = (lane >> 4) * 8;
        const int rA = lane & 15;
        s16x8 a0 = *(const s16x8*)&Asm[(wr * 32 + rA) * 40 + koff];
        s16x8 a1 = *(const s16x8*)&Asm[(wr * 32 + 16 + rA) * 40 + koff];
#pragma unroll
        for (int ni = 0; ni < 4; ++ni) {
            s16x8 b = *(const s16x8*)&Bsm[(wc * 64 + ni * 16 + rA) * 40 + koff];
            acc[0][ni] = __builtin_amdgcn_mfma_f32_16x16x32_bf16(a0, b, acc[0][ni], 0, 0, 0);
            acc[1][ni] = __builtin_amdgcn_mfma_f32_16x16x32_bf16(a1, b, acc[1][ni], 0, 0, 0);
        }
        __syncthreads();
    }
    const int jb = wc * 64 + (lane & 15);
#pragma unroll
    for (int mi = 0; mi < 2; ++mi) {
#pragma unroll
        for (int reg = 0; reg < 4; ++reg) {
            const int rloc = wr * 32 + mi * 16 + (lane >> 4) * 4 + reg;
            const int rowg = i0 + rloc;
#pragma unroll
            for (int ni = 0; ni < 4; ++ni) {
                const int j = jb + ni * 16;
                float v = acc[mi][ni][reg];
                if (rowg < N_NODES) {
                    v += yagg[rowg * HID + j] + b1[j];
                    v = fmaxf(v, 0.f);
                } else v = 0.f;
                Hsm[rloc * 136 + j] = f2bf(v);
            }
        }
    }
    __syncthreads();
    f32x4 acc2[2][4];
#pragma unroll
    for (int mi = 0; mi < 2; ++mi)
#pragma unroll
        for (int ni = 0; ni < 4; ++ni) acc2[mi][ni] = zero;

    for (int ks = 0; ks < 4; ++ks) {
        STAGE_B(Bsm, &W2t[ks * 32], HID);
        __syncthreads();
        const int koff = (lane >> 4) * 8;
        const int rA = lane & 15;
        s16x8 a0 = *(const s16x8*)&Hsm[(wr * 32 + rA) * 136 + ks * 32 + koff];
        s16x8 a1 = *(const s16x8*)&Hsm[(wr * 32 + 16 + rA) * 136 + ks * 32 + koff];
#pragma unroll
        for (int ni = 0; ni < 4; ++ni) {
            s16x8 b = *(const s16x8*)&Bsm[(wc * 64 + ni * 16 + rA) * 40 + koff];
            acc2[0][ni] = __builtin_amdgcn_mfma_f32_16x16x32_bf16(a0, b, acc2[0][ni], 0, 0, 0);
            acc2[1][ni] = __builtin_amdgcn_mfma_f32_16x16x32_bf16(a1, b, acc2[1][ni], 0, 0, 0);
        }
        __syncthreads();
    }
#pragma unroll
    for (int mi = 0; mi < 2; ++mi) {
#pragma unroll
        for (int reg = 0; reg < 4; ++reg) {
            const int rloc = wr * 32 + mi * 16 + (lane >> 4) * 4 + reg;
            const int rowg = i0 + rloc;
            if (rowg < N_NODES) {
#pragma unroll
                for (int ni = 0; ni < 4; ++ni) {
                    const int j = jb + ni * 16;
                    float v = acc2[mi][ni][reg] + b2[j];
                    r1b[rowg * HID + j] = f2bf(fmaxf(v, 0.f));
                }
            }
        }
    }
}

// ---- conv2 message pass (sorted, bf16 gather) -----------------------------
__global__ __launch_bounds__(256) void k_edge2(const unsigned short* __restrict__ r1b,
                                               const int* __restrict__ ss2,
                                               const int* __restrict__ ds2,
                                               const float* __restrict__ eas,
                                               const float* __restrict__ e2w,
                                               const float* __restrict__ e2b,
                                               float* __restrict__ agg2) {
    __shared__ float w_s[7 * HID];
    __shared__ float b_s[HID];
    __shared__ float Csm[64 * 129];
    __shared__ float ea_s[64 * 8];
    __shared__ int ss_s[64];
    __shared__ int ds_s[64];
    const int t = threadIdx.x;
    const int e0 = blockIdx.x * 64;
    for (int i = t; i < 7 * HID; i += 256) w_s[i] = e2w[i];
    if (t < HID) b_s[t] = e2b[t];
    if (t < 64) ss_s[t] = ss2[e0 + t];
    else if (t < 128) ds_s[t - 64] = ds2[e0 + (t - 64)];
    for (int i = t; i < 512; i += 256) ea_s[i] = eas[e0 * 8 + i];
    __syncthreads();

    const int r = t >> 2, c0 = (t & 3) * 32;
    const int s = ss_s[r];
    float eav[7];
#pragma unroll
    for (int q = 0; q < 7; ++q) eav[q] = ea_s[r * 8 + q];
    const s16x8* rp = (const s16x8*)&r1b[s * HID + c0];
#pragma unroll
    for (int u = 0; u < 4; ++u) {
        s16x8 hv = rp[u];
#pragma unroll
        for (int j = 0; j < 8; ++j) {
            const int c = c0 + u * 8 + j;
            float v = bf2f(hv[j]) + b_s[c];
#pragma unroll
            for (int q = 0; q < 7; ++q) v = fmaf(eav[q], w_s[q * HID + c], v);
            Csm[r * 129 + c] = fmaxf(v, 0.f);
        }
    }
    __syncthreads();
    if (t < 128) {
        float ssum = 0.f;
        int prev = ds_s[0];
        for (int rr = 0; rr < 64; ++rr) {
            const int d = ds_s[rr];
            const float v = Csm[rr * 129 + t];
            if (d != prev) { atomicAdd(&agg2[prev * HID + t], ssum); ssum = 0.f; prev = d; }
            ssum += v;
        }
        atomicAdd(&agg2[prev * HID + t], ssum);
    }
}

// -------- node MLP2: r2 = bf16(relu(relu((r1b+agg2)@V1 + b1)@V2 + b2)) -----
__global__ __launch_bounds__(256) void k_node2(const unsigned short* __restrict__ r1b,
                                               const float* __restrict__ agg2,
                                               const unsigned short* __restrict__ V1t,
                                               const unsigned short* __restrict__ V2t,
                                               const float* __restrict__ b1,
                                               const float* __restrict__ b2,
                                               unsigned short* __restrict__ r2) {
    __shared__ __align__(16) unsigned short Asm[64 * 40];
    __shared__ __align__(16) unsigned short Bsm[128 * 40];
    __shared__ __align__(16) unsigned short Hsm[64 * 136];
    const int t = threadIdx.x;
    const int i0 = blockIdx.x * 64;
    const int lane = t & 63, wid = t >> 6, wr = wid >> 1, wc = wid & 1;
    const int r = t >> 2, kc = (t & 3) * 8;
    const int rg = i0 + r;
    const bool rvalid = rg < N_NODES;

    f32x4 acc[2][4];
    const f32x4 zero = {0.f, 0.f, 0.f, 0.f};
#pragma unroll
    for (int mi = 0; mi < 2; ++mi)
#pragma unroll
        for (int ni = 0; ni < 4; ++ni) acc[mi][ni] = zero;

    for (int ks = 0; ks < 4; ++ks) {
        {
            const int kb = ks * 32 + kc;
            s16x8 v;
            if (rvalid) {
                const s16x8 ra = *(const s16x8*)&r1b[rg * HID + kb];
                const f32x4* pb = (const f32x4*)&agg2[rg * HID + kb];
                f32x4 w0 = pb[0], w1 = pb[1];
#pragma unroll
                for (int j = 0; j < 4; ++j) v[j] = (short)f2bf(bf2f(ra[j]) + w0[j]);
#pragma unroll
                for (int j = 0; j < 4; ++j) v[4 + j] = (short)f2bf(bf2f(ra[4 + j]) + w1[j]);
            } else {
#pragma unroll
                for (int j = 0; j < 8; ++j) v[j] = 0;
            }
            *(s16x8*)&Asm[r * 40 + kc] = v;
        }
        STAGE_B(Bsm, &V1t[ks * 32], HID);
        __syncthreads();
        const int koff = (lane >> 4) * 8;
        const int rA = lane & 15;
        s16x8 a0 = *(const s16x8*)&Asm[(wr * 32 + rA) * 40 + koff];
        s16x8 a1 = *(const s16x8*)&Asm[(wr * 32 + 16 + rA) * 40 + koff];
#pragma unroll
        for (int ni = 0; ni < 4; ++ni) {
            s16x8 b = *(const s16x8*)&Bsm[(wc * 64 + ni * 16 + rA) * 40 + koff];
            acc[0][ni] = __builtin_amdgcn_mfma_f32_16x16x32_bf16(a0, b, acc[0][ni], 0, 0, 0);
            acc[1][ni] = __builtin_amdgcn_mfma_f32_16x16x32_bf16(a1, b, acc[1][ni], 0, 0, 0);
        }
        __syncthreads();
    }
    const int jb = wc * 64 + (lane & 15);
#pragma unroll
    for (int mi = 0; mi < 2; ++mi) {
#pragma unroll
        for (int reg = 0; reg < 4; ++reg) {
            const int rloc = wr * 32 + mi * 16 + (lane >> 4) * 4 + reg;
            const int rowg = i0 + rloc;
#pragma unroll
            for (int ni = 0; ni < 4; ++ni) {
                const int j = jb + ni * 16;
                float v = acc[mi][ni][reg];
                if (rowg < N_NODES) {
                    v += b1[j];
                    v = fmaxf(v, 0.f);
                } else v = 0.f;
                Hsm[rloc * 136 + j] = f2bf(v);
            }
        }
    }
    __syncthreads();
    f32x4 acc2[2][4];
#pragma unroll
    for (int mi = 0; mi < 2; ++mi)
#pragma unroll
        for (int ni = 0; ni < 4; ++ni) acc2[mi][ni] = zero;

    for (int ks = 0; ks < 4; ++ks) {
        STAGE_B(Bsm, &V2t[ks * 32], HID);
        __syncthreads();
        const int koff = (lane >> 4) * 8;
        const int rA = lane & 15;
        s16x8 a0 = *(const s16x8*)&Hsm[(wr * 32 + rA) * 136 + ks * 32 + koff];
        s16x8 a1 = *(const s16x8*)&Hsm[(wr * 32 + 16 + rA) * 136 + ks * 32 + koff];
#pragma unroll
        for (int ni = 0; ni < 4; ++ni) {
            s16x8 b = *(const s16x8*)&Bsm[(wc * 64 + ni * 16 + rA) * 40 + koff];
            acc2[0][ni] = __builtin_amdgcn_mfma_f32_16x16x32_bf16(a0, b, acc2[0][ni], 0, 0, 0);
            acc2[1][ni] = __builtin_amdgcn_mfma_f32_16x16x32_bf16(a1, b, acc2[1][ni], 0, 0, 0);
        }
        __syncthreads();
    }
#pragma unroll
    for (int mi = 0; mi < 2; ++mi) {
#pragma unroll
        for (int reg = 0; reg < 4; ++reg) {
            const int rloc = wr * 32 + mi * 16 + (lane >> 4) * 4 + reg;
            const int rowg = i0 + rloc;
            if (rowg < N_NODES) {
#pragma unroll
                for (int ni = 0; ni < 4; ++ni) {
                    const int j = jb + ni * 16;
                    float v = acc2[mi][ni][reg] + b2[j];
                    r2[rowg * HID + j] = f2bf(fmaxf(v, 0.f));
                }
            }
        }
    }
}

// ------- edge head: out = relu([r2_s|r2_d|ea] @ em_w1 + b1) @ em_w2 + b2 ---
__global__ __launch_bounds__(256) void k_head(const unsigned short* __restrict__ r2,
                                              const int* __restrict__ srcp,
                                              const int* __restrict__ dstp,
                                              const float* __restrict__ ea,
                                              const unsigned short* __restrict__ EW1t,
                                              const float* __restrict__ emw1,
                                              const float* __restrict__ emb1,
                                              const float* __restrict__ emw2,
                                              const float* __restrict__ emb2,
                                              float* __restrict__ out) {
    __shared__ __align__(16) unsigned short Asm[64 * 40];
    __shared__ __align__(16) unsigned short Bsm[128 * 40];
    __shared__ float Hsm[64 * 129];
    __shared__ float ew_ea[7 * HID];
    __shared__ float eb1_s[HID];
    __shared__ float w2_s[256];
    __shared__ float b2_s[2];
    __shared__ float ea_s[64 * 8];
    __shared__ int src_s[64];
    __shared__ int dst_s[64];
    __shared__ float red[512];
    const int t = threadIdx.x;
    const int e0 = blockIdx.x * 64;

    for (int i = t; i < 7 * HID; i += 256) ew_ea[i] = emw1[256 * HID + i];
    if (t < HID) eb1_s[t] = emb1[t];
    if (t < 256) w2_s[t] = emw2[t];
    if (t < 2) b2_s[t] = emb2[t];
    for (int i = t; i < 64 * 7; i += 256) {
        int r = i / 7, q = i - r * 7;
        ea_s[r * 8 + q] = ea[(e0 + r) * 7 + q];
    }
    if (t < 64) src_s[t] = srcp[e0 + t];
    else if (t < 128) dst_s[t - 64] = dstp[e0 + (t - 64)];
    __syncthreads();

    const int lane = t & 63, wid = t >> 6, wr = wid >> 1, wc = wid & 1;
    const int r = t >> 2, kc = (t & 3) * 8;

    f32x4 acc[2][4];
    const f32x4 zero = {0.f, 0.f, 0.f, 0.f};
#pragma unroll
    for (int mi = 0; mi < 2; ++mi)
#pragma unroll
        for (int ni = 0; ni < 4; ++ni) acc[mi][ni] = zero;

    for (int ks = 0; ks < 8; ++ks) {
        {
            const int k = ks * 32 + kc;
            const unsigned short* p = (k < HID) ? &r2[src_s[r] * HID + k]
                                                : &r2[dst_s[r] * HID + (k - HID)];
            *(s16x8*)&Asm[r * 40 + kc] = *(const s16x8*)p;
        }
        STAGE_B(Bsm, &EW1t[ks * 32], 256);
        __syncthreads();
        const int koff = (lane >> 4) * 8;
        const int rA = lane & 15;
        s16x8 a0 = *(const s16x8*)&Asm[(wr * 32 + rA) * 40 + koff];
        s16x8 a1 = *(const s16x8*)&Asm[(wr * 32 + 16 + rA) * 40 + koff];
#pragma unroll
        for (int ni = 0; ni < 4; ++ni) {
            s16x8 b = *(const s16x8*)&Bsm[(wc * 64 + ni * 16 + rA) * 40 + koff];
            acc[0][ni] = __builtin_amdgcn_mfma_f32_16x16x32_bf16(a0, b, acc[0][ni], 0, 0, 0);
            acc[1][ni] = __builtin_amdgcn_mfma_f32_16x16x32_bf16(a1, b, acc[1][ni], 0, 0, 0);
        }
        __syncthreads();
    }
    const int jb = wc * 64 + (lane & 15);
#pragma unroll
    for (int mi = 0; mi < 2; ++mi) {
#pragma unroll
        for (int reg = 0; reg < 4; ++reg) {
            const int rloc = wr * 32 + mi * 16 + (lane >> 4) * 4 + reg;
#pragma unroll
            for (int ni = 0; ni < 4; ++ni) {
                const int j = jb + ni * 16;
                float v = acc[mi][ni][reg] + eb1_s[j];
#pragma unroll
                for (int q = 0; q < 7; ++q)
                    v = fmaf(ea_s[rloc * 8 + q], ew_ea[q * HID + j], v);
                Hsm[rloc * 129 + j] = fmaxf(v, 0.f);
            }
        }
    }
    __syncthreads();
    {
        const int e = t & 63, p = t >> 6;
        const float* hb = &Hsm[e * 129 + p * 32];
        float s0 = 0.f, s1 = 0.f;
#pragma unroll
        for (int j = 0; j < 32; ++j) {
            const float h = hb[j];
            s0 = fmaf(h, w2_s[(p * 32 + j) * 2], s0);
            s1 = fmaf(h, w2_s[(p * 32 + j) * 2 + 1], s1);
        }
        red[(e * 4 + p) * 2] = s0;
        red[(e * 4 + p) * 2 + 1] = s1;
    }
    __syncthreads();
    if (t < 64) {
        float o0 = b2_s[0], o1 = b2_s[1];
#pragma unroll
        for (int p = 0; p < 4; ++p) {
            o0 += red[(t * 4 + p) * 2];
            o1 += red[(t * 4 + p) * 2 + 1];
        }
        out[(e0 + t) * 2] = o0;
        out[(e0 + t) * 2 + 1] = o1;
    }
}

// ---------------------------------------------------------------------------
extern "C" void kernel_launch(void* const* d_in, const int* in_sizes, int n_in,
                              void* d_out, int out_size, void* d_ws, size_t ws_size,
                              hipStream_t stream) {
    (void)in_sizes; (void)n_in; (void)out_size; (void)ws_size;
    const float* x    = (const float*)d_in[0];
    const unsigned* eidx = (const unsigned*)d_in[1];
    const float* ea   = (const float*)d_in[2];
    const float* e1w  = (const float*)d_in[3];
    const float* e1b  = (const float*)d_in[4];
    const float* m1w1 = (const float*)d_in[5];
    const float* m1b1 = (const float*)d_in[6];
    const float* m1w2 = (const float*)d_in[7];
    const float* m1b2 = (const float*)d_in[8];
    const float* e2w  = (const float*)d_in[9];
    const float* e2b  = (const float*)d_in[10];
    const float* m2w1 = (const float*)d_in[11];
    const float* m2b1 = (const float*)d_in[12];
    const float* m2w2 = (const float*)d_in[13];
    const float* m2b2 = (const float*)d_in[14];
    const float* emw1 = (const float*)d_in[15];
    const float* emb1 = (const float*)d_in[16];
    const float* emw2 = (const float*)d_in[17];
    const float* emb2 = (const float*)d_in[18];
    float* out = (float*)d_out;

    char* ws = (char*)d_ws;
    float* yagg = (float*)(ws + 0);                            // 51.2 MB (reused as agg2)
    unsigned short* r1b = (unsigned short*)(ws + 51200000);    // 25.6 MB
    unsigned short* r2  = (unsigned short*)(ws + 76800000);    // 25.6 MB (aliases eas)
    float* eas          = (float*)(ws + 76800000);             // 19.2 MB (dead before r2 written)
    unsigned short* xbf = (unsigned short*)(ws + 102400000);   // 83.2 MB
    unsigned short* W1t  = (unsigned short*)(ws + 185600000);  // 106,496
    unsigned short* W2t  = (unsigned short*)(ws + 185706496);
    unsigned short* V1t  = (unsigned short*)(ws + 185739264);
    unsigned short* V2t  = (unsigned short*)(ws + 185772032);
    unsigned short* EW1t = (unsigned short*)(ws + 185804800);  // ends 185,870,336
    int* s32  = (int*)(ws + 185870336);
    int* d32  = (int*)(ws + 188270336);
    int* ss2  = (int*)(ws + 190670336);
    int* ds2  = (int*)(ws + 193070336);
    int* cnt  = (int*)(ws + 195470336);                        // 400 KB
    int* bsum = (int*)(ws + 195870336);                        // 4 KB

    hipMemsetAsync(yagg, 0, (size_t)N_NODES * HID * 4, stream);
    hipMemsetAsync(cnt, 0, (size_t)N_NODES * 4, stream);
    k_decode<<<2344, 256, 0, stream>>>(eidx, s32, d32);
    k_prep<<<528, 256, 0, stream>>>(m1w1, m1w2, m2w1, m2w2, emw1, W1t, W2t, V1t, V2t, EW1t);
    k_castx<<<(N_NODES * 52 + 255) / 256, 256, 0, stream>>>(x, xbf);
    k_hist<<<2344, 256, 0, stream>>>(d32, cnt);
    k_scanA<<<NB_SCAN, 256, 0, stream>>>(cnt, bsum);
    k_scanC<<<NB_SCAN, 256, 0, stream>>>(cnt, bsum);
    k_scatter<<<2344, 256, 0, stream>>>(s32, d32, ea, cnt, ss2, ds2, eas);
    k_edge1<<<N_EDGES / 64, 256, 0, stream>>>(xbf, ss2, ds2, eas, e1w, e1b, W1t, yagg);
    k_node1<<<(N_NODES + 63) / 64, 256, 0, stream>>>(xbf, yagg, W1t, W2t, m1b1, m1b2, r1b);
    hipMemsetAsync(yagg, 0, (size_t)N_NODES * HID * 4, stream);
    k_edge2<<<N_EDGES / 64, 256, 0, stream>>>(r1b, ss2, ds2, eas, e2w, e2b, yagg);
    k_node2<<<(N_NODES + 63) / 64, 256, 0, stream>>>(r1b, yagg, V1t, V2t, m2b1, m2b2, r2);
    k_head<<<N_EDGES / 64, 256, 0, stream>>>(r2, s32, d32, ea, EW1t, emw1, emb1, emw2, emb2, out);
}